// Round 1
// baseline (5420.414 us; speedup 1.0000x reference)
//
#include <hip/hip_runtime.h>
#include <math.h>

#define TT 512
#define BB 32
#define DD 1280

// ---------------------------------------------------------------------------
// Kernel 1: x-projection GEMM.  XP[m][n] = bias[n] + sum_k X[m][k]*Wx[n][k]
// M = T*B = 16384, N = K = D = 1280.  fp32 (no fp32 MFMA on CDNA4).
// Unchanged (~700 us); the scan is still the dominant cost.
// ---------------------------------------------------------------------------
__launch_bounds__(256) __global__
void xproj_gemm(const float* __restrict__ X, const float* __restrict__ Wx,
                const float* __restrict__ bias, float* __restrict__ XP)
{
    __shared__ __align__(16) float As[16][64];
    __shared__ __align__(16) float Bs[16][64];
    const int tid = threadIdx.x;
    const int n0 = blockIdx.x * 64;
    const int m0 = blockIdx.y * 64;
    const int lm = tid >> 2;
    const int lk = (tid & 3) << 2;
    const int tn = tid & 15;
    const int tm = tid >> 4;

    float acc[4][4] = {};
    for (int k0 = 0; k0 < DD; k0 += 16) {
        float4 av = *(const float4*)(X  + (size_t)(m0 + lm) * DD + k0 + lk);
        float4 bv = *(const float4*)(Wx + (size_t)(n0 + lm) * DD + k0 + lk);
        __syncthreads();
        As[lk + 0][lm] = av.x; As[lk + 1][lm] = av.y;
        As[lk + 2][lm] = av.z; As[lk + 3][lm] = av.w;
        Bs[lk + 0][lm] = bv.x; Bs[lk + 1][lm] = bv.y;
        Bs[lk + 2][lm] = bv.z; Bs[lk + 3][lm] = bv.w;
        __syncthreads();
#pragma unroll
        for (int k = 0; k < 16; ++k) {
            float4 a4 = *(const float4*)&As[k][tm << 2];
            float4 b4 = *(const float4*)&Bs[k][tn << 2];
            float a[4] = {a4.x, a4.y, a4.z, a4.w};
            float b[4] = {b4.x, b4.y, b4.z, b4.w};
#pragma unroll
            for (int i = 0; i < 4; ++i)
#pragma unroll
                for (int j = 0; j < 4; ++j)
                    acc[i][j] += a[i] * b[j];
        }
    }
    float4 bv = *(const float4*)(bias + n0 + (tn << 2));
    float bias4[4] = {bv.x, bv.y, bv.z, bv.w};
#pragma unroll
    for (int i = 0; i < 4; ++i) {
        float4 o;
        o.x = acc[i][0] + bias4[0];
        o.y = acc[i][1] + bias4[1];
        o.z = acc[i][2] + bias4[2];
        o.w = acc[i][3] + bias4[3];
        *(float4*)(XP + (size_t)(m0 + (tm << 2) + i) * DD + n0 + (tn << 2)) = o;
    }
}

// ---------------------------------------------------------------------------
// Device-scope (LLC-coherent) 8-byte tagged word helpers.
// Word layout: low 32 = float bits of h, high 32 = step tag.
// A single relaxed agent-scope 8B atomic is both the data AND the flag:
// no drain, no separate counter, no ordering between stores needed.
// ---------------------------------------------------------------------------
__device__ __forceinline__ unsigned long long ld_agent_u64(const unsigned long long* p) {
    return __hip_atomic_load(p, __ATOMIC_RELAXED, __HIP_MEMORY_SCOPE_AGENT);
}
__device__ __forceinline__ void st_agent_u64(unsigned long long* p, unsigned long long v) {
    __hip_atomic_store(p, v, __ATOMIC_RELAXED, __HIP_MEMORY_SCOPE_AGENT);
}

// Init the 2-slot tagged ring: slot0 = h0 with tag 0, slot1 = invalid tag.
// (Re-run on every graph replay, so leftover tags from a prior run are benign.)
__global__ void init_hist(const float* __restrict__ h0,
                          unsigned long long* __restrict__ ht)
{
    int idx = blockIdx.x * 256 + threadIdx.x;
    if (idx < BB * DD) {
        ht[idx]           = (unsigned long long)__float_as_uint(h0[idx]); // tag 0
        ht[BB * DD + idx] = 0xFFFFFFFF00000000ull;                        // never matches
    }
}

// ---------------------------------------------------------------------------
// Kernel 2: persistent gated-Elman scan.
//   4 batch-groups x 8 batches; 64 WGs/group, each owns 20 W_h rows.
//   R5 changes vs R4:
//   (1) W_h fragment lives in 200 persistent VGPRs per thread (1 wave/SIMD ->
//       512-VGPR budget). Wlds deleted; LDS = Hlds 40 KB only. Cuts the
//       compute loop from 9 to 4 ds_read_b128 per k-iter.
//   (2) Tagged-word publish: h values carry their step tag in one 8B word.
//       Consumers retry-load their 40 words directly (batched rounds, all
//       stale words reloaded pipelined). Removes s_waitcnt(0) drain, counter
//       store, counter poll, and one barrier -> ~3 serial LLC RTs per step
//       collapse to the single unavoidable data RT.
//   Ring-of-2 slot safety: publishing tag t requires having verified all tags
//   t-1 (barrier-ordered within the WG), so any writer of tag t+1 into slot
//   (t-1)&1 runs strictly after every peer finished reading slot (t-1)&1.
// ---------------------------------------------------------------------------
__launch_bounds__(256, 1) __global__
void gated_scan(const float* __restrict__ XP, const float* __restrict__ Z,
                const float* __restrict__ Wh, float* __restrict__ OUT,
                unsigned long long* __restrict__ ht)
{
    const int w   = blockIdx.x;
    const int g   = w >> 6;       // batch group 0..3
    const int idx = w & 63;       // e-slice within group
    const int b0  = g << 3;       // first of 8 batches
    const int e0  = idx * 20;     // first of 20 W_h rows
    const int tid = threadIdx.x;
    const int u   = tid >> 5;     // 0..7
    const int p   = tid & 31;     // d-split lane
    const int bh  = u >> 2;       // 0..1 -> batches b0+4*bh+i
    const int eq  = u & 3;        // 0..3 -> e-rows e0+5*eq+j

    __shared__ __align__(16) float Hlds[8 * DD];    // 40.0 KB (only LDS)

    // Persistent per-thread W fragment: W[e0+5*eq+j][4p+128k], j<5, k<10.
    // 50 float4 = 200 VGPRs, loaded once (reads W_h 8x total across the grid).
    const int d0 = p << 2;
    float4 wreg[5][10];
#pragma unroll
    for (int j = 0; j < 5; ++j)
#pragma unroll
        for (int k = 0; k < 10; ++k)
            wreg[j][k] = *(const float4*)(Wh + (size_t)(e0 + eq * 5 + j) * DD
                                             + d0 + (k << 7));

    const int  o   = p;
    const bool fin = (p < 20);
    const int  bb  = b0 + (bh << 2) + o / 5;
    const int  ee  = e0 + eq * 5 + o % 5;

    for (int t = 1; t <= TT; ++t) {
        // prefetch xp/z (independent of h -> overlaps the tagged wait)
        const size_t oidx = ((size_t)(t - 1) * BB + bb) * DD + ee;
        float xpv = 0.f, zv = 0.f;
        if (fin) { xpv = XP[oidx]; zv = Z[oidx]; }

        // Tagged load of the group's unique 8x1280 h block for step t-1.
        // 40 words/thread, strided i*256+tid (per-instruction coalesced).
        const unsigned long long* hs =
            ht + (size_t)((t - 1) & 1) * (BB * DD) + (size_t)b0 * DD;
        const unsigned tag = (unsigned)(t - 1);
        unsigned long long v[40];
#pragma unroll
        for (int i = 0; i < 40; ++i)
            v[i] = ld_agent_u64(hs + i * 256 + tid);
        // Batched retry: each round re-issues ALL stale loads pipelined
        // (never a serial per-word dependent chain).
        bool bad;
        do {
            bad = false;
#pragma unroll
            for (int i = 0; i < 40; ++i)
                if ((unsigned)(v[i] >> 32) != tag) {
                    v[i] = ld_agent_u64(hs + i * 256 + tid);
                    bad = true;
                }
        } while (bad);

        __syncthreads();   // (A) prev-step Hlds reads fully consumed
#pragma unroll
        for (int i = 0; i < 40; ++i)
            Hlds[i * 256 + tid] = __uint_as_float((unsigned)v[i]);
        __syncthreads();   // (B) Hlds ready

        float acc[4][5] = {};
#pragma unroll
        for (int k = 0; k < 10; ++k) {
            const int d = d0 + (k << 7);
            float4 h4[4];
#pragma unroll
            for (int i = 0; i < 4; ++i)
                h4[i] = *(const float4*)&Hlds[((bh << 2) + i) * DD + d];
#pragma unroll
            for (int i = 0; i < 4; ++i)
#pragma unroll
                for (int j = 0; j < 5; ++j)
                    acc[i][j] += h4[i].x * wreg[j][k].x + h4[i].y * wreg[j][k].y
                               + h4[i].z * wreg[j][k].z + h4[i].w * wreg[j][k].w;
        }

        // all-reduce over the 32 d-split lanes (bit5 = unit bit, untouched)
#pragma unroll
        for (int m = 16; m >= 1; m >>= 1)
#pragma unroll
            for (int i = 0; i < 4; ++i)
#pragma unroll
                for (int j = 0; j < 5; ++j)
                    acc[i][j] += __shfl_xor(acc[i][j], m, 64);

        if (fin) {
            float sum = acc[0][0];
#pragma unroll
            for (int q = 1; q < 20; ++q)
                sum = (o == q) ? acc[q / 5][q % 5] : sum;
            const float hn = tanhf(xpv + sum);
            const float sg = zv / (1.0f + __expf(-zv));
            OUT[oidx] = hn * sg;
            // fire-and-forget tagged publish: data and flag are one atom
            st_agent_u64(ht + (size_t)(t & 1) * (BB * DD) + (size_t)bb * DD + ee,
                         ((unsigned long long)(unsigned)t << 32) |
                         (unsigned long long)__float_as_uint(hn));
            if (t == TT)
                OUT[(size_t)TT * BB * DD + (size_t)bb * DD + ee] = hn;
        }
    }
}

// ---------------------------------------------------------------------------
extern "C" void kernel_launch(void* const* d_in, const int* in_sizes, int n_in,
                              void* d_out, int out_size, void* d_ws, size_t ws_size,
                              hipStream_t stream) {
    const float* x    = (const float*)d_in[0];  // [T,B,D]
    const float* z    = (const float*)d_in[1];  // [T,B,D]
    const float* h0   = (const float*)d_in[2];  // [B,D]
    const float* Wx   = (const float*)d_in[3];  // [D,D]
    const float* Wh   = (const float*)d_in[4];  // [D,D]
    const float* bias = (const float*)d_in[5];  // [D]
    float* out = (float*)d_out;

    // ws layout: xp 83.9 MB | tagged 2-slot h ring 655 KB
    float* xp = (float*)d_ws;
    unsigned long long* ht = (unsigned long long*)(xp + (size_t)TT * BB * DD);

    init_hist<<<(BB * DD + 255) / 256, 256, 0, stream>>>(h0, ht);

    dim3 ggrid(DD / 64, (TT * BB) / 64);  // (20, 256)
    xproj_gemm<<<ggrid, 256, 0, stream>>>(x, Wx, bias, xp);
    gated_scan<<<256, 256, 0, stream>>>(xp, z, Wh, out, ht);
}

// Round 2
// 4477.793 us; speedup vs baseline: 1.2105x; 1.2105x over previous
//
#include <hip/hip_runtime.h>
#include <math.h>

#define TT 512
#define BB 32
#define DD 1280

// ---------------------------------------------------------------------------
// Kernel 1: x-projection GEMM.  XP[m][n] = bias[n] + sum_k X[m][k]*Wx[n][k]
// M = T*B = 16384, N = K = D = 1280.  fp32 (no fp32 MFMA on CDNA4).
// Unchanged (~700 us); the scan is still the dominant cost.
// ---------------------------------------------------------------------------
__launch_bounds__(256) __global__
void xproj_gemm(const float* __restrict__ X, const float* __restrict__ Wx,
                const float* __restrict__ bias, float* __restrict__ XP)
{
    __shared__ __align__(16) float As[16][64];
    __shared__ __align__(16) float Bs[16][64];
    const int tid = threadIdx.x;
    const int n0 = blockIdx.x * 64;
    const int m0 = blockIdx.y * 64;
    const int lm = tid >> 2;
    const int lk = (tid & 3) << 2;
    const int tn = tid & 15;
    const int tm = tid >> 4;

    float acc[4][4] = {};
    for (int k0 = 0; k0 < DD; k0 += 16) {
        float4 av = *(const float4*)(X  + (size_t)(m0 + lm) * DD + k0 + lk);
        float4 bv = *(const float4*)(Wx + (size_t)(n0 + lm) * DD + k0 + lk);
        __syncthreads();
        As[lk + 0][lm] = av.x; As[lk + 1][lm] = av.y;
        As[lk + 2][lm] = av.z; As[lk + 3][lm] = av.w;
        Bs[lk + 0][lm] = bv.x; Bs[lk + 1][lm] = bv.y;
        Bs[lk + 2][lm] = bv.z; Bs[lk + 3][lm] = bv.w;
        __syncthreads();
#pragma unroll
        for (int k = 0; k < 16; ++k) {
            float4 a4 = *(const float4*)&As[k][tm << 2];
            float4 b4 = *(const float4*)&Bs[k][tn << 2];
            float a[4] = {a4.x, a4.y, a4.z, a4.w};
            float b[4] = {b4.x, b4.y, b4.z, b4.w};
#pragma unroll
            for (int i = 0; i < 4; ++i)
#pragma unroll
                for (int j = 0; j < 4; ++j)
                    acc[i][j] += a[i] * b[j];
        }
    }
    float4 bv = *(const float4*)(bias + n0 + (tn << 2));
    float bias4[4] = {bv.x, bv.y, bv.z, bv.w};
#pragma unroll
    for (int i = 0; i < 4; ++i) {
        float4 o;
        o.x = acc[i][0] + bias4[0];
        o.y = acc[i][1] + bias4[1];
        o.z = acc[i][2] + bias4[2];
        o.w = acc[i][3] + bias4[3];
        *(float4*)(XP + (size_t)(m0 + (tm << 2) + i) * DD + n0 + (tn << 2)) = o;
    }
}

// ---------------------------------------------------------------------------
// Device-scope (LLC-coherent) 8-byte tagged word helpers.
// Word layout: low 32 = float bits of h, high 32 = step tag.
// ---------------------------------------------------------------------------
__device__ __forceinline__ unsigned long long ld_agent_u64(const unsigned long long* p) {
    return __hip_atomic_load(p, __ATOMIC_RELAXED, __HIP_MEMORY_SCOPE_AGENT);
}
__device__ __forceinline__ void st_agent_u64(unsigned long long* p, unsigned long long v) {
    __hip_atomic_store(p, v, __ATOMIC_RELAXED, __HIP_MEMORY_SCOPE_AGENT);
}

// Init the 2-slot tagged ring: slot0 = h0 with tag 0, slot1 = invalid tag.
__global__ void init_hist(const float* __restrict__ h0,
                          unsigned long long* __restrict__ ht)
{
    int idx = blockIdx.x * 256 + threadIdx.x;
    if (idx < BB * DD) {
        ht[idx]           = (unsigned long long)__float_as_uint(h0[idx]); // tag 0
        ht[BB * DD + idx] = 0xFFFFFFFF00000000ull;                        // never matches
    }
}

// ---------------------------------------------------------------------------
// Kernel 2: persistent gated-Elman scan.  R6 regrouping:
//   8 batch-groups x 4 batches; 32 WGs/group, each owns 40 W_h rows.
//   Rationale (R4/R5 post-mortem): per-step cost tracks the agent-scope
//   coherent-traffic volume = WGs x Gb x 5KB (every consumer re-reads its
//   whole group block).  Gb 8->4 halves that (10.5 -> 5.2 MB/round) and
//   halves the producer count gating each consumer (64 -> 32).
//   W_h slice (40 rows) is staged through LDS then register-loaded; the LDS
//   is overwritten afterwards, so the compiler CANNOT rematerialize the
//   loads (R5 failure: VGPR=192 < 200 -> W re-fetched per step, +385 MB HBM).
//   200 persistent VGPRs/thread, budget 512 at 1 wave/SIMD.
//   Sync protocol: tagged 8B words, 2-slot ring (HW-validated R5); poll is
//   now 20 words/thread.
// ---------------------------------------------------------------------------
__launch_bounds__(256, 1) __global__
void gated_scan(const float* __restrict__ XP, const float* __restrict__ Z,
                const float* __restrict__ Wh, float* __restrict__ OUT,
                unsigned long long* __restrict__ ht)
{
    const int w   = blockIdx.x;
    const int g   = w >> 5;       // batch group 0..7
    const int idx = w & 31;       // e-slice within group
    const int b0  = g << 2;       // first of 4 batches
    const int e0  = idx * 40;     // first of 40 W_h rows
    const int tid = threadIdx.x;
    const int u   = tid >> 5;     // 0..7 -> e-row block
    const int p   = tid & 31;     // d-split lane

    // S is multi-purpose LDS: W staging chunks (25.6 KB), then the per-step
    // h block Hlds[4][1280] (20 KB).
    __shared__ __align__(16) float S[8 * DD];    // 40 KB

    // ---- one-time: W fragment -> 200 persistent VGPRs per thread ----------
    // thread (u,p) holds W[e0 + 5u + j][4p + 128k], j<5, k<10.
    const int d0 = p << 2;
    float4 wreg[5][10];
#pragma unroll 1
    for (int c = 0; c < 8; ++c) {
        __syncthreads();
        const float* src = Wh + (size_t)(e0 + 5 * c) * DD;   // 5 rows = 1600 f4
        for (int i = tid; i < 5 * DD / 4; i += 256)
            ((float4*)S)[i] = ((const float4*)src)[i];
        __syncthreads();
        if (u == c) {
#pragma unroll
            for (int j = 0; j < 5; ++j)
#pragma unroll
                for (int k = 0; k < 10; ++k)
                    wreg[j][k] = *(const float4*)&S[j * DD + d0 + (k << 7)];
        }
    }

    const int  o   = p;
    const bool fin = (p < 20);
    const int  bb  = b0 + o / 5;             // batch of this lane's output
    const int  ee  = e0 + u * 5 + o % 5;     // e-row of this lane's output

    for (int t = 1; t <= TT; ++t) {
        // prefetch xp/z (independent of h -> overlaps the tagged wait)
        const size_t oidx = ((size_t)(t - 1) * BB + bb) * DD + ee;
        float xpv = 0.f, zv = 0.f;
        if (fin) { xpv = XP[oidx]; zv = Z[oidx]; }

        // Tagged load of the group's unique 4x1280 h block for step t-1.
        // 20 words/thread, strided i*256+tid (per-instruction coalesced).
        const unsigned long long* hs =
            ht + (size_t)((t - 1) & 1) * (BB * DD) + (size_t)b0 * DD;
        const unsigned tag = (unsigned)(t - 1);
        unsigned long long v[20];
#pragma unroll
        for (int i = 0; i < 20; ++i)
            v[i] = ld_agent_u64(hs + i * 256 + tid);
        bool bad;
        do {
            bad = false;
#pragma unroll
            for (int i = 0; i < 20; ++i)
                if ((unsigned)(v[i] >> 32) != tag) {
                    v[i] = ld_agent_u64(hs + i * 256 + tid);
                    bad = true;
                }
        } while (bad);

        __syncthreads();   // (A) prev-step S reads fully consumed
#pragma unroll
        for (int i = 0; i < 20; ++i)
            S[i * 256 + tid] = __uint_as_float((unsigned)v[i]);
        __syncthreads();   // (B) h block ready in S[4][1280]

        float acc[4][5] = {};
#pragma unroll
        for (int k = 0; k < 10; ++k) {
            const int d = d0 + (k << 7);
            float4 h4[4];
#pragma unroll
            for (int i = 0; i < 4; ++i)
                h4[i] = *(const float4*)&S[i * DD + d];
#pragma unroll
            for (int i = 0; i < 4; ++i)
#pragma unroll
                for (int j = 0; j < 5; ++j)
                    acc[i][j] += h4[i].x * wreg[j][k].x + h4[i].y * wreg[j][k].y
                               + h4[i].z * wreg[j][k].z + h4[i].w * wreg[j][k].w;
        }

        // all-reduce over the 32 d-split lanes (bit5 = u bit, untouched)
#pragma unroll
        for (int m = 16; m >= 1; m >>= 1)
#pragma unroll
            for (int i = 0; i < 4; ++i)
#pragma unroll
                for (int j = 0; j < 5; ++j)
                    acc[i][j] += __shfl_xor(acc[i][j], m, 64);

        if (fin) {
            float sum = acc[0][0];
#pragma unroll
            for (int q = 1; q < 20; ++q)
                sum = (o == q) ? acc[q / 5][q % 5] : sum;
            const float hn = tanhf(xpv + sum);
            const float sg = zv / (1.0f + __expf(-zv));
            OUT[oidx] = hn * sg;
            // fire-and-forget tagged publish: data and flag are one atom
            st_agent_u64(ht + (size_t)(t & 1) * (BB * DD) + (size_t)bb * DD + ee,
                         ((unsigned long long)(unsigned)t << 32) |
                         (unsigned long long)__float_as_uint(hn));
            if (t == TT)
                OUT[(size_t)TT * BB * DD + (size_t)bb * DD + ee] = hn;
        }
    }
}

// ---------------------------------------------------------------------------
extern "C" void kernel_launch(void* const* d_in, const int* in_sizes, int n_in,
                              void* d_out, int out_size, void* d_ws, size_t ws_size,
                              hipStream_t stream) {
    const float* x    = (const float*)d_in[0];  // [T,B,D]
    const float* z    = (const float*)d_in[1];  // [T,B,D]
    const float* h0   = (const float*)d_in[2];  // [B,D]
    const float* Wx   = (const float*)d_in[3];  // [D,D]
    const float* Wh   = (const float*)d_in[4];  // [D,D]
    const float* bias = (const float*)d_in[5];  // [D]
    float* out = (float*)d_out;

    // ws layout: xp 83.9 MB | tagged 2-slot h ring 655 KB
    float* xp = (float*)d_ws;
    unsigned long long* ht = (unsigned long long*)(xp + (size_t)TT * BB * DD);

    init_hist<<<(BB * DD + 255) / 256, 256, 0, stream>>>(h0, ht);

    dim3 ggrid(DD / 64, (TT * BB) / 64);  // (20, 256)
    xproj_gemm<<<ggrid, 256, 0, stream>>>(x, Wx, bias, xp);
    gated_scan<<<256, 256, 0, stream>>>(xp, z, Wh, out, ht);
}

// Round 3
// 4329.917 us; speedup vs baseline: 1.2519x; 1.0342x over previous
//
#include <hip/hip_runtime.h>
#include <math.h>

#define TT 512
#define BB 32
#define DD 1280

// ---------------------------------------------------------------------------
// Kernel 1: x-projection GEMM.  XP[m][n] = bias[n] + sum_k X[m][k]*Wx[n][k]
// M = T*B = 16384, N = K = D = 1280.  fp32 (no fp32 MFMA on CDNA4).
// Unchanged (~700 us); revisit once the scan is below ~2x of it.
// ---------------------------------------------------------------------------
__launch_bounds__(256) __global__
void xproj_gemm(const float* __restrict__ X, const float* __restrict__ Wx,
                const float* __restrict__ bias, float* __restrict__ XP)
{
    __shared__ __align__(16) float As[16][64];
    __shared__ __align__(16) float Bs[16][64];
    const int tid = threadIdx.x;
    const int n0 = blockIdx.x * 64;
    const int m0 = blockIdx.y * 64;
    const int lm = tid >> 2;
    const int lk = (tid & 3) << 2;
    const int tn = tid & 15;
    const int tm = tid >> 4;

    float acc[4][4] = {};
    for (int k0 = 0; k0 < DD; k0 += 16) {
        float4 av = *(const float4*)(X  + (size_t)(m0 + lm) * DD + k0 + lk);
        float4 bv = *(const float4*)(Wx + (size_t)(n0 + lm) * DD + k0 + lk);
        __syncthreads();
        As[lk + 0][lm] = av.x; As[lk + 1][lm] = av.y;
        As[lk + 2][lm] = av.z; As[lk + 3][lm] = av.w;
        Bs[lk + 0][lm] = bv.x; Bs[lk + 1][lm] = bv.y;
        Bs[lk + 2][lm] = bv.z; Bs[lk + 3][lm] = bv.w;
        __syncthreads();
#pragma unroll
        for (int k = 0; k < 16; ++k) {
            float4 a4 = *(const float4*)&As[k][tm << 2];
            float4 b4 = *(const float4*)&Bs[k][tn << 2];
            float a[4] = {a4.x, a4.y, a4.z, a4.w};
            float b[4] = {b4.x, b4.y, b4.z, b4.w};
#pragma unroll
            for (int i = 0; i < 4; ++i)
#pragma unroll
                for (int j = 0; j < 4; ++j)
                    acc[i][j] += a[i] * b[j];
        }
    }
    float4 bv = *(const float4*)(bias + n0 + (tn << 2));
    float bias4[4] = {bv.x, bv.y, bv.z, bv.w};
#pragma unroll
    for (int i = 0; i < 4; ++i) {
        float4 o;
        o.x = acc[i][0] + bias4[0];
        o.y = acc[i][1] + bias4[1];
        o.z = acc[i][2] + bias4[2];
        o.w = acc[i][3] + bias4[3];
        *(float4*)(XP + (size_t)(m0 + (tm << 2) + i) * DD + n0 + (tn << 2)) = o;
    }
}

// ---------------------------------------------------------------------------
// Device-scope (LLC-coherent) helpers.
// Tagged h word: low 32 = float bits, high 32 = step tag.
// ---------------------------------------------------------------------------
__device__ __forceinline__ unsigned long long ld_agent_u64(const unsigned long long* p) {
    return __hip_atomic_load(p, __ATOMIC_RELAXED, __HIP_MEMORY_SCOPE_AGENT);
}
__device__ __forceinline__ void st_agent_u64(unsigned long long* p, unsigned long long v) {
    __hip_atomic_store(p, v, __ATOMIC_RELAXED, __HIP_MEMORY_SCOPE_AGENT);
}
__device__ __forceinline__ unsigned ld_agent_u32(const unsigned* p) {
    return __hip_atomic_load(p, __ATOMIC_RELAXED, __HIP_MEMORY_SCOPE_AGENT);
}
__device__ __forceinline__ void st_agent_u32(unsigned* p, unsigned v) {
    __hip_atomic_store(p, v, __ATOMIC_RELAXED, __HIP_MEMORY_SCOPE_AGENT);
}

// Init: slot0 = h0 with tag 0, slot1 = invalid tag, per-wave flags = 0.
__global__ void init_hist(const float* __restrict__ h0,
                          unsigned long long* __restrict__ ht,
                          unsigned* __restrict__ flags)
{
    int idx = blockIdx.x * 256 + threadIdx.x;
    if (idx < BB * DD) {
        ht[idx]           = (unsigned long long)__float_as_uint(h0[idx]); // tag 0
        ht[BB * DD + idx] = 0xFFFFFFFF00000000ull;                        // never matches
    }
    if (idx < 8 * 32 * 4) flags[idx] = 0;
}

// ---------------------------------------------------------------------------
// Kernel 2: persistent gated-Elman scan.
//   8 batch-groups x 4 batches; 32 WGs/group, each owns 40 W_h rows.
//   W_h slice forced into 200 persistent regs/thread via LDS round-trip
//   (R5 lesson: plain global loads get rematerialized).
//   R7 changes vs R6 (all arithmetic bitwise-identical to R6):
//   (1) Detection/data decoupling: producers publish a per-WAVE monotonic
//       flag after s_waitcnt(0) (R3/R4-validated drain-then-publish).
//       Consumers spin on ONE 4B flag per thread (128 flags/group) instead
//       of re-loading the 40KB tagged block per poll round (was 10.5 MB of
//       LLC traffic per round grid-wide -> fabric self-congestion).  The
//       tagged bulk load runs once and is verified inline (retry = rare
//       safety net; correctness never depends on flag ordering).
//   (2) Reduce-scatter shuffle tree: 21 shfl_xor instead of 100 (same
//       binary summation tree -> bitwise-identical sums); exactly 20 of 32
//       lanes end up holding the 20 outputs; the 20-deep select chain dies.
//   (3) One barrier/step: h block double-buffered in LDS (2 x 20KB); step
//       t+1's writes target the opposite buffer from step t's readers.
// ---------------------------------------------------------------------------
__launch_bounds__(256, 1) __global__
void gated_scan(const float* __restrict__ XP, const float* __restrict__ Z,
                const float* __restrict__ Wh, float* __restrict__ OUT,
                unsigned long long* __restrict__ ht,
                unsigned* __restrict__ flags)
{
    const int w   = blockIdx.x;
    const int g   = w >> 5;       // batch group 0..7
    const int idx = w & 31;       // e-slice within group
    const int b0  = g << 2;       // first of 4 batches
    const int e0  = idx * 40;     // first of 40 W_h rows
    const int tid = threadIdx.x;
    const int u   = tid >> 5;     // 0..7 -> e-row block
    const int p   = tid & 31;     // d-split lane

    // S: W staging chunks (25.6 KB) pre-loop, then double-buffered h
    // blocks S[2][4][1280] (2 x 20 KB) in the scan.
    __shared__ __align__(16) float S[2 * 4 * DD];    // 40 KB

    // ---- one-time: W fragment -> 200 persistent regs per thread ----------
    // thread (u,p) holds W[e0 + 5u + j][4p + 128k], j<5, k<10.
    const int d0 = p << 2;
    float4 wreg[5][10];
#pragma unroll 1
    for (int c = 0; c < 8; ++c) {
        __syncthreads();
        const float* src = Wh + (size_t)(e0 + 5 * c) * DD;   // 5 rows
        for (int i = tid; i < 5 * DD / 4; i += 256)
            ((float4*)S)[i] = ((const float4*)src)[i];
        __syncthreads();
        if (u == c) {
#pragma unroll
            for (int j = 0; j < 5; ++j)
#pragma unroll
                for (int k = 0; k < 10; ++k)
                    wreg[j][k] = *(const float4*)&S[j * DD + d0 + (k << 7)];
        }
    }
    __syncthreads();   // staging region overlaps h buffer 1; fence before use

    // Output lane mapping for the reduce-scatter tree (see tree below):
    // valid low-3 patterns {0,1,2,4,5} hold acc j = {0,1,2,3,4}; bits 3,4
    // give the batch index i = b8 + 2*b16.  Exactly 20 valid lanes per
    // 32-lane group = the 20 outputs.
    const int  lo3 = p & 7;
    const bool fin = (lo3 != 3) && (lo3 < 6);
    const int  jj  = (lo3 < 3) ? lo3 : (lo3 - 1);          // 0,1,2,4->3,5->4
    const int  ii  = ((p >> 3) & 1) + (((p >> 4) & 1) << 1);
    const int  bb  = b0 + ii;
    const int  ee  = e0 + u * 5 + jj;

    const unsigned* fl = flags + (g << 7) + (tid & 127);   // my spin word
    unsigned* myflag = flags + (g << 7) + (idx << 2) + (tid >> 6);

    for (int t = 1; t <= TT; ++t) {
        // prefetch xp/z (independent of h -> overlaps detection)
        const size_t oidx = ((size_t)(t - 1) * BB + bb) * DD + ee;
        float xpv = 0.f, zv = 0.f;
        if (fin) { xpv = XP[oidx]; zv = Z[oidx]; }

        // ---- detection: per-thread 4B flag spin (128 flags cover the
        //      group's 32 WGs x 4 waves; threads 128..255 mirror) ----------
        const unsigned need = (unsigned)(t - 1);
        while (ld_agent_u32(fl) < need) {}

        // ---- data: one tagged bulk load + inline verify (retry rare) ----
        const unsigned long long* hs =
            ht + (size_t)((t - 1) & 1) * (BB * DD) + (size_t)b0 * DD;
        unsigned long long v[20];
#pragma unroll
        for (int i = 0; i < 20; ++i)
            v[i] = ld_agent_u64(hs + i * 256 + tid);
        bool bad;
        do {
            bad = false;
#pragma unroll
            for (int i = 0; i < 20; ++i)
                if ((unsigned)(v[i] >> 32) != need) {
                    v[i] = ld_agent_u64(hs + i * 256 + tid);
                    bad = true;
                }
        } while (bad);

        // double-buffered h stage: step t uses buffer t&1
        float* Sh = S + (size_t)(t & 1) * (4 * DD);
#pragma unroll
        for (int i = 0; i < 20; ++i)
            Sh[i * 256 + tid] = __uint_as_float((unsigned)v[i]);
        __syncthreads();   // the only barrier per step

        float acc[4][5] = {};
#pragma unroll
        for (int k = 0; k < 10; ++k) {
            const int d = d0 + (k << 7);
            float4 h4[4];
#pragma unroll
            for (int i = 0; i < 4; ++i)
                h4[i] = *(const float4*)&Sh[i * DD + d];
#pragma unroll
            for (int i = 0; i < 4; ++i)
#pragma unroll
                for (int j = 0; j < 5; ++j)
                    acc[i][j] += h4[i].x * wreg[j][k].x + h4[i].y * wreg[j][k].y
                               + h4[i].z * wreg[j][k].z + h4[i].w * wreg[j][k].w;
        }

        // ---- reduce-scatter over the 32 d-split lanes (bit5 untouched).
        // Same pairwise tree as the full butterfly -> bitwise-identical.
        float s[20];
#pragma unroll
        for (int i = 0; i < 4; ++i)
#pragma unroll
            for (int j = 0; j < 5; ++j)
                s[i * 5 + j] = acc[i][j];
        // m=16: 20 -> 10
#pragma unroll
        for (int i = 0; i < 10; ++i) {
            float send = (p & 16) ? s[i] : s[10 + i];
            float recv = __shfl_xor(send, 16, 64);
            s[i] = ((p & 16) ? s[10 + i] : s[i]) + recv;
        }
        // m=8: 10 -> 5
#pragma unroll
        for (int i = 0; i < 5; ++i) {
            float send = (p & 8) ? s[i] : s[5 + i];
            float recv = __shfl_xor(send, 8, 64);
            s[i] = ((p & 8) ? s[5 + i] : s[i]) + recv;
        }
        // m=4: 5 -> 3 (pad)
        s[5] = 0.f;
#pragma unroll
        for (int i = 0; i < 3; ++i) {
            float send = (p & 4) ? s[i] : s[3 + i];
            float recv = __shfl_xor(send, 4, 64);
            s[i] = ((p & 4) ? s[3 + i] : s[i]) + recv;
        }
        // m=2: 3 -> 2 (pad)
        s[3] = 0.f;
#pragma unroll
        for (int i = 0; i < 2; ++i) {
            float send = (p & 2) ? s[i] : s[2 + i];
            float recv = __shfl_xor(send, 2, 64);
            s[i] = ((p & 2) ? s[2 + i] : s[i]) + recv;
        }
        // m=1: 2 -> 1
        {
            float send = (p & 1) ? s[0] : s[1];
            float recv = __shfl_xor(send, 1, 64);
            s[0] = ((p & 1) ? s[1] : s[0]) + recv;
        }

        if (fin) {
            const float hn = tanhf(xpv + s[0]);
            const float sg = zv / (1.0f + __expf(-zv));
            OUT[oidx] = hn * sg;
            // tagged publish: data and readiness are one atom
            st_agent_u64(ht + (size_t)(t & 1) * (BB * DD) + (size_t)bb * DD + ee,
                         ((unsigned long long)(unsigned)t << 32) |
                         (unsigned long long)__float_as_uint(hn));
            if (t == TT)
                OUT[(size_t)TT * BB * DD + (size_t)bb * DD + ee] = hn;
        }
        // drain own publishes to the coherence point, then raise the
        // per-wave flag (hint only; tags carry correctness).
        __builtin_amdgcn_s_waitcnt(0);
        if ((tid & 63) == 0)
            st_agent_u32(myflag, (unsigned)t);
    }
}

// ---------------------------------------------------------------------------
extern "C" void kernel_launch(void* const* d_in, const int* in_sizes, int n_in,
                              void* d_out, int out_size, void* d_ws, size_t ws_size,
                              hipStream_t stream) {
    const float* x    = (const float*)d_in[0];  // [T,B,D]
    const float* z    = (const float*)d_in[1];  // [T,B,D]
    const float* h0   = (const float*)d_in[2];  // [B,D]
    const float* Wx   = (const float*)d_in[3];  // [D,D]
    const float* Wh   = (const float*)d_in[4];  // [D,D]
    const float* bias = (const float*)d_in[5];  // [D]
    float* out = (float*)d_out;

    // ws layout: xp 83.9 MB | tagged 2-slot h ring 655 KB | wave flags 4 KB
    float* xp = (float*)d_ws;
    unsigned long long* ht = (unsigned long long*)(xp + (size_t)TT * BB * DD);
    unsigned* flags = (unsigned*)(ht + 2 * (size_t)BB * DD);

    init_hist<<<(BB * DD + 255) / 256, 256, 0, stream>>>(h0, ht, flags);

    dim3 ggrid(DD / 64, (TT * BB) / 64);  // (20, 256)
    xproj_gemm<<<ggrid, 256, 0, stream>>>(x, Wx, bias, xp);
    gated_scan<<<256, 256, 0, stream>>>(xp, z, Wh, out, ht, flags);
}